// Round 2
// baseline (704.650 us; speedup 1.0000x reference)
//
#include <hip/hip_runtime.h>
#include <hip/hip_fp16.h>
#include <math.h>

#define D 128
#define GM 64            // rows per GEMM tile in fused kernel
#define CONV_BLOCKS 2048
#define SCAT_BLOCKS 1024
#define HIST_BLOCKS 1024
#define CONV_BLOCKS_OLD 1024
#define NBSHIFT 6        // 64 nodes per src bucket (16 KB of Yh)
#define NBINS 2048       // covers N up to 131072

typedef _Float16 f16x8 __attribute__((ext_vector_type(8)));
typedef float    f32x4 __attribute__((ext_vector_type(4)));
typedef _Float16 h2_t  __attribute__((ext_vector_type(2)));

__device__ __forceinline__ float dot2acc(unsigned ua, unsigned ub, float c) {
#if __has_builtin(__builtin_amdgcn_fdot2)
  return __builtin_amdgcn_fdot2(__builtin_bit_cast(h2_t, ua),
                                __builtin_bit_cast(h2_t, ub), c, false);
#else
  __half2 a = __builtin_bit_cast(__half2, ua);
  __half2 b = __builtin_bit_cast(__half2, ub);
  float2 fa = __half22float2(a), fb = __half22float2(b);
  return fmaf(fa.x, fb.x, fmaf(fa.y, fb.y, c));
#endif
}

__device__ __forceinline__ unsigned pack2(float x, float y) {
  __half2 h;
  h.x = __float2half_rn(x);
  h.y = __float2half_rn(y);
  return __builtin_bit_cast(unsigned, h);
}

// ---------------- K-A: setup — blocks 0-7 transpose W -> WhT fp16; block 8 zeroes cnt
__global__ __launch_bounds__(256) void setup_kernel(const float* __restrict__ W,
                                                    __half* __restrict__ WhT,
                                                    int* __restrict__ cnt) {
  if ((int)blockIdx.x < 8) {
    const int n  = blockIdx.x * 16 + (threadIdx.x >> 4);
    const int k0 = (threadIdx.x & 15) * 8;
    float w[8];
    #pragma unroll
    for (int kk = 0; kk < 8; kk++) w[kk] = W[(k0 + kk) * D + n];
    uint4 u;
    u.x = pack2(w[0], w[1]); u.y = pack2(w[2], w[3]);
    u.z = pack2(w[4], w[5]); u.w = pack2(w[6], w[7]);
    *(uint4*)(WhT + n * D + k0) = u;
  } else {
    for (int i = threadIdx.x; i < NBINS; i += 256) cnt[i] = 0;
  }
}

// ---------------- K-B: histogram of src buckets ----------------
__global__ __launch_bounds__(256) void hist_kernel(const int* __restrict__ eidx,
                                                   int* __restrict__ cnt, int E) {
  for (int e = blockIdx.x * 256 + threadIdx.x; e < E; e += HIST_BLOCKS * 256)
    atomicAdd(&cnt[eidx[e] >> NBSHIFT], 1);
}

// ---------------- K-C: exclusive scan of cnt -> cursor (single block) ----------
__global__ __launch_bounds__(256) void scan_kernel(const int* __restrict__ cnt,
                                                   int* __restrict__ cursor) {
  __shared__ int tsum[256];
  const int tid = threadIdx.x;
  int v[NBINS / 256];
  int s = 0;
  #pragma unroll
  for (int j = 0; j < NBINS / 256; j++) {
    v[j] = cnt[tid * (NBINS / 256) + j];
    s += v[j];
  }
  tsum[tid] = s;
  __syncthreads();
  for (int off = 1; off < 256; off <<= 1) {
    int t = (tid >= off) ? tsum[tid - off] : 0;
    __syncthreads();
    tsum[tid] += t;
    __syncthreads();
  }
  int ex = (tid > 0) ? tsum[tid - 1] : 0;
  #pragma unroll
  for (int j = 0; j < NBINS / 256; j++) {
    cursor[tid * (NBINS / 256) + j] = ex;
    ex += v[j];
  }
}

// ---------------- K-D: fused GEMM (Y = Xout @ W) + Xin convert + edge scatter --
__global__ __launch_bounds__(256) void fused_kernel(
    const float* __restrict__ Xout, const float* __restrict__ Xin,
    const __half* __restrict__ WhT, __half* __restrict__ Yh,
    __half* __restrict__ Xh, const int* __restrict__ eidx,
    int2* __restrict__ sortedSD, int* __restrict__ sortedE,
    int* __restrict__ cursor, int N, int E, int gemm_blocks)
{
  __shared__ __align__(16) __half sA[GM * D];   // 16 KB; reused as sC in epilogue

  const int tid = threadIdx.x;
  const int bid = blockIdx.x;

  if (bid >= gemm_blocks + CONV_BLOCKS) {
    // ---- scatter role: counting-sort edges by src bucket ----
    const int sb = bid - gemm_blocks - CONV_BLOCKS;
    for (int e = sb * 256 + tid; e < E; e += SCAT_BLOCKS * 256) {
      int s = eidx[e];
      int d = eidx[E + e];
      int pos = atomicAdd(&cursor[s >> NBSHIFT], 1);
      sortedSD[pos] = make_int2(s, d);
      sortedE[pos]  = e;
    }
    return;
  }

  if (bid >= gemm_blocks) {
    // ---- convert role: Xh = (half)Xin ----
    const int cb = bid - gemm_blocks;
    const int n4 = N * (D / 4);
    const int stride = CONV_BLOCKS * 256 * 4;
    for (int base = (cb * 256 + tid) * 4; base < n4; base += stride) {
      float4 v[4];
      #pragma unroll
      for (int j = 0; j < 4; j++)
        if (base + j < n4) v[j] = ((const float4*)Xin)[base + j];
      #pragma unroll
      for (int j = 0; j < 4; j++)
        if (base + j < n4) {
          uint2 u;
          u.x = pack2(v[j].x, v[j].y);
          u.y = pack2(v[j].z, v[j].w);
          ((uint2*)Xh)[base + j] = u;
        }
    }
    return;
  }

  // ---- GEMM role ----
  const int row0 = bid * GM;

  float4 v[8];
  #pragma unroll
  for (int i = 0; i < 4; i++) {
    int gi = tid + i * 256;            // granule id 0..1023
    int r = gi >> 4, q = gi & 15;
    int gr = row0 + r;
    if (gr < N) {
      const float4* s = (const float4*)(Xout + (size_t)gr * D + q * 8);
      v[2*i]   = s[0];
      v[2*i+1] = s[1];
    } else {
      v[2*i]   = make_float4(0.f, 0.f, 0.f, 0.f);
      v[2*i+1] = make_float4(0.f, 0.f, 0.f, 0.f);
    }
  }
  #pragma unroll
  for (int i = 0; i < 4; i++) {
    int gi = tid + i * 256;
    int r = gi >> 4, q = gi & 15;
    uint4 u;
    u.x = pack2(v[2*i].x,   v[2*i].y);
    u.y = pack2(v[2*i].z,   v[2*i].w);
    u.z = pack2(v[2*i+1].x, v[2*i+1].y);
    u.w = pack2(v[2*i+1].z, v[2*i+1].w);
    *(uint4*)(sA + r * D + ((q ^ (r & 7)) << 3)) = u;   // XOR swizzle
  }
  __syncthreads();

  const int lane = tid & 63, wave = tid >> 6;
  const int m = lane & 15, quad = lane >> 4;
  const int rloc = wave * 16 + m;

  f32x4 acc[8];
  #pragma unroll
  for (int ct = 0; ct < 8; ct++) acc[ct] = (f32x4){0.f, 0.f, 0.f, 0.f};

  #pragma unroll
  for (int ks = 0; ks < 4; ks++) {
    const int g = ks * 4 + quad;
    f16x8 bfrag[8];
    #pragma unroll
    for (int ct = 0; ct < 8; ct++)
      bfrag[ct] = *(const f16x8*)(WhT + (size_t)(ct * 16 + m) * D + g * 8);
    f16x8 afrag = *(const f16x8*)(sA + rloc * D + ((g ^ (rloc & 7)) << 3));
    #pragma unroll
    for (int ct = 0; ct < 8; ct++)
      acc[ct] = __builtin_amdgcn_mfma_f32_16x16x32_f16(
          afrag, bfrag[ct], acc[ct], 0, 0, 0);
  }

  __syncthreads();
  __half* sC = sA;
  #pragma unroll
  for (int ct = 0; ct < 8; ct++)
    #pragma unroll
    for (int reg = 0; reg < 4; reg++) {
      int r = wave * 16 + quad * 4 + reg;
      sC[r * D + ct * 16 + m] = __float2half_rn(acc[ct][reg]);
    }
  __syncthreads();
  #pragma unroll
  for (int i = 0; i < 4; i++) {
    int gi = tid + i * 256;
    int r = gi >> 4, q = gi & 15;
    int gr = row0 + r;
    if (gr < N)
      *(uint4*)(Yh + (size_t)gr * D + q * 8) = *(const uint4*)(sC + r * D + q * 8);
  }
}

// ---------------- K-E: sorted edge kernel, XCD-bijective swizzle, 2 edges/group -
__global__ __launch_bounds__(256) void edge_sorted_kernel(
    const __half* __restrict__ Yh, const __half* __restrict__ Xh,
    const int2* __restrict__ sortedSD, const int* __restrict__ sortedE,
    float* __restrict__ out, int E)
{
  // bijective XCD swizzle: each XCD owns a contiguous range of sorted edges
  const int nwg = gridDim.x, orig = blockIdx.x;
  const int xcd = orig & 7, rest = orig >> 3;
  const int q8 = nwg >> 3, r8 = nwg & 7;
  const int wg = (xcd < r8) ? (xcd * (q8 + 1) + rest)
                            : (r8 * (q8 + 1) + (xcd - r8) * q8 + rest);

  long long gid = (long long)wg * 256 + threadIdx.x;
  int grp = (int)(gid >> 4);
  int l   = (int)(gid & 15);
  int e0 = grp * 2;
  if (e0 >= E) return;
  bool has1 = (e0 + 1 < E);

  int2 sd0 = sortedSD[e0];
  int2 sd1 = has1 ? sortedSD[e0 + 1] : sd0;

  uint4 a0 = ((const uint4*)(Yh + (size_t)sd0.x * D))[l];
  uint4 b0 = ((const uint4*)(Xh + (size_t)sd0.y * D))[l];
  uint4 a1 = ((const uint4*)(Yh + (size_t)sd1.x * D))[l];
  uint4 b1 = ((const uint4*)(Xh + (size_t)sd1.y * D))[l];

  float p = 0.f, qd = 0.f;
  p = dot2acc(a0.x, b0.x, p);  qd = dot2acc(a1.x, b1.x, qd);
  p = dot2acc(a0.y, b0.y, p);  qd = dot2acc(a1.y, b1.y, qd);
  p = dot2acc(a0.z, b0.z, p);  qd = dot2acc(a1.z, b1.z, qd);
  p = dot2acc(a0.w, b0.w, p);  qd = dot2acc(a1.w, b1.w, qd);

  p  += __shfl_xor(p, 8);   qd += __shfl_xor(qd, 8);
  p  += __shfl_xor(p, 4);   qd += __shfl_xor(qd, 4);
  p  += __shfl_xor(p, 2);   qd += __shfl_xor(qd, 2);
  p  += __shfl_xor(p, 1);   qd += __shfl_xor(qd, 1);

  if (l == 0) {
    out[sortedE[e0]] = 1.0f / (1.0f + __expf(-p));
    if (has1) out[sortedE[e0 + 1]] = 1.0f / (1.0f + __expf(-qd));
  }
}

// ---------------- Round-1 fallback kernels (ws too small for sort arrays) ------
__global__ __launch_bounds__(256) void prep2_kernel(
    const float* __restrict__ Xout, const float* __restrict__ Xin,
    const __half* __restrict__ WhT, __half* __restrict__ Yh,
    __half* __restrict__ Xh, int N, int gemm_blocks)
{
  __shared__ __align__(16) __half sA[GM * D];

  const int tid = threadIdx.x;

  if ((int)blockIdx.x >= gemm_blocks) {
    const int cb = blockIdx.x - gemm_blocks;
    const int n4 = N * (D / 4);
    const int stride = CONV_BLOCKS * 256 * 4;
    for (int base = (cb * 256 + tid) * 4; base < n4; base += stride) {
      float4 v[4];
      #pragma unroll
      for (int j = 0; j < 4; j++)
        if (base + j < n4) v[j] = ((const float4*)Xin)[base + j];
      #pragma unroll
      for (int j = 0; j < 4; j++)
        if (base + j < n4) {
          uint2 u;
          u.x = pack2(v[j].x, v[j].y);
          u.y = pack2(v[j].z, v[j].w);
          ((uint2*)Xh)[base + j] = u;
        }
    }
    return;
  }

  const int row0 = blockIdx.x * GM;

  float4 v[8];
  #pragma unroll
  for (int i = 0; i < 4; i++) {
    int gi = tid + i * 256;
    int r = gi >> 4, q = gi & 15;
    int gr = row0 + r;
    if (gr < N) {
      const float4* s = (const float4*)(Xout + (size_t)gr * D + q * 8);
      v[2*i]   = s[0];
      v[2*i+1] = s[1];
    } else {
      v[2*i]   = make_float4(0.f, 0.f, 0.f, 0.f);
      v[2*i+1] = make_float4(0.f, 0.f, 0.f, 0.f);
    }
  }
  #pragma unroll
  for (int i = 0; i < 4; i++) {
    int gi = tid + i * 256;
    int r = gi >> 4, q = gi & 15;
    uint4 u;
    u.x = pack2(v[2*i].x,   v[2*i].y);
    u.y = pack2(v[2*i].z,   v[2*i].w);
    u.z = pack2(v[2*i+1].x, v[2*i+1].y);
    u.w = pack2(v[2*i+1].z, v[2*i+1].w);
    *(uint4*)(sA + r * D + ((q ^ (r & 7)) << 3)) = u;
  }
  __syncthreads();

  const int lane = tid & 63, wave = tid >> 6;
  const int m = lane & 15, quad = lane >> 4;
  const int rloc = wave * 16 + m;

  f32x4 acc[8];
  #pragma unroll
  for (int ct = 0; ct < 8; ct++) acc[ct] = (f32x4){0.f, 0.f, 0.f, 0.f};

  #pragma unroll
  for (int ks = 0; ks < 4; ks++) {
    const int g = ks * 4 + quad;
    f16x8 bfrag[8];
    #pragma unroll
    for (int ct = 0; ct < 8; ct++)
      bfrag[ct] = *(const f16x8*)(WhT + (size_t)(ct * 16 + m) * D + g * 8);
    f16x8 afrag = *(const f16x8*)(sA + rloc * D + ((g ^ (rloc & 7)) << 3));
    #pragma unroll
    for (int ct = 0; ct < 8; ct++)
      acc[ct] = __builtin_amdgcn_mfma_f32_16x16x32_f16(
          afrag, bfrag[ct], acc[ct], 0, 0, 0);
  }

  __syncthreads();
  __half* sC = sA;
  #pragma unroll
  for (int ct = 0; ct < 8; ct++)
    #pragma unroll
    for (int reg = 0; reg < 4; reg++) {
      int r = wave * 16 + quad * 4 + reg;
      sC[r * D + ct * 16 + m] = __float2half_rn(acc[ct][reg]);
    }
  __syncthreads();
  #pragma unroll
  for (int i = 0; i < 4; i++) {
    int gi = tid + i * 256;
    int r = gi >> 4, q = gi & 15;
    int gr = row0 + r;
    if (gr < N)
      *(uint4*)(Yh + (size_t)gr * D + q * 8) = *(const uint4*)(sC + r * D + q * 8);
  }
}

__global__ __launch_bounds__(256) void edge_dot2_kernel(
    const __half* __restrict__ Yh, const __half* __restrict__ Xh,
    const int* __restrict__ idx, float* __restrict__ out, int E)
{
  long long gid = (long long)blockIdx.x * 256 + threadIdx.x;
  int slot = (int)(gid >> 4);
  int l    = (int)(gid & 15);
  int e0 = slot * 2;
  if (e0 >= E) return;
  int e1 = e0 + 1;
  bool has1 = (e1 < E);

  int s0 = idx[e0];
  int d0 = idx[E + e0];
  int s1 = has1 ? idx[e1] : s0;
  int d1 = has1 ? idx[E + e1] : d0;

  uint4 a0 = ((const uint4*)(Yh + (size_t)s0 * D))[l];
  uint4 b0 = ((const uint4*)(Xh + (size_t)d0 * D))[l];
  uint4 a1 = ((const uint4*)(Yh + (size_t)s1 * D))[l];
  uint4 b1 = ((const uint4*)(Xh + (size_t)d1 * D))[l];

  float p = 0.f, q = 0.f;
  p = dot2acc(a0.x, b0.x, p);  q = dot2acc(a1.x, b1.x, q);
  p = dot2acc(a0.y, b0.y, p);  q = dot2acc(a1.y, b1.y, q);
  p = dot2acc(a0.z, b0.z, p);  q = dot2acc(a1.z, b1.z, q);
  p = dot2acc(a0.w, b0.w, p);  q = dot2acc(a1.w, b1.w, q);

  p += __shfl_xor(p, 8);  q += __shfl_xor(q, 8);
  p += __shfl_xor(p, 4);  q += __shfl_xor(q, 4);
  p += __shfl_xor(p, 2);  q += __shfl_xor(q, 2);
  p += __shfl_xor(p, 1);  q += __shfl_xor(q, 1);

  if (l == 0) {
    float2 o;
    o.x = 1.0f / (1.0f + __expf(-p));
    o.y = 1.0f / (1.0f + __expf(-q));
    if (has1) *(float2*)(out + e0) = o;
    else      out[e0] = o.x;
  }
}

__global__ __launch_bounds__(256) void edge_bilinear_direct_kernel(
    const float* __restrict__ Xout, const float* __restrict__ Xin,
    const float* __restrict__ W, const int* __restrict__ idx,
    float* __restrict__ out, int E)
{
  long long gid = (long long)blockIdx.x * 256 + threadIdx.x;
  int e = (int)(gid >> 6);
  if (e >= E) return;
  int l = (int)(gid & 63);

  int src = idx[e];
  int dst = idx[E + e];
  const float* a = Xout + (size_t)src * D;
  const float* b = Xin  + (size_t)dst * D;

  float s = 0.f;
  #pragma unroll
  for (int kk = 0; kk < 2; kk++) {
    int k = l + kk * 64;
    float ak = a[k];
    float t = 0.f;
    #pragma unroll 8
    for (int j = 0; j < D; j++) t = fmaf(W[(size_t)k * D + j], b[j], t);
    s = fmaf(ak, t, s);
  }
  #pragma unroll
  for (int off = 32; off >= 1; off >>= 1) s += __shfl_xor(s, off);
  if (l == 0) out[e] = 1.0f / (1.0f + __expf(-s));
}

extern "C" void kernel_launch(void* const* d_in, const int* in_sizes, int n_in,
                              void* d_out, int out_size, void* d_ws, size_t ws_size,
                              hipStream_t stream) {
  const float* x_in  = (const float*)d_in[0];   // [N, 128]
  const float* x_out = (const float*)d_in[1];   // [N, 128]
  const int*   eidx  = (const int*)d_in[2];     // [2, E]
  const float* W     = (const float*)d_in[3];   // [128,128]
  float* out = (float*)d_out;

  const int N = in_sizes[0] / D;
  const int E = in_sizes[2] / 2;

  const size_t half_rows = (size_t)N * D * sizeof(__half);  // 25.6 MB each
  const size_t wht_bytes = (size_t)D * D * sizeof(__half);  // 32 KB
  const size_t cnt_bytes = (size_t)NBINS * sizeof(int);     // 8 KB
  const size_t sd_bytes  = (size_t)E * sizeof(int2);        // 12.8 MB
  const size_t se_bytes  = (size_t)E * sizeof(int);         // 6.4 MB

  size_t off_yh  = 0;
  size_t off_xh  = off_yh + half_rows;
  size_t off_wht = off_xh + half_rows;
  size_t off_cnt = off_wht + wht_bytes;
  size_t off_cur = off_cnt + cnt_bytes;
  size_t off_sd  = off_cur + cnt_bytes;
  size_t off_se  = off_sd + sd_bytes;
  size_t total_ws = off_se + se_bytes;

  if (ws_size >= total_ws && N <= (NBINS << NBSHIFT)) {
    __half* Yh   = (__half*)((char*)d_ws + off_yh);
    __half* Xh   = (__half*)((char*)d_ws + off_xh);
    __half* WhT  = (__half*)((char*)d_ws + off_wht);
    int*  cnt    = (int*)((char*)d_ws + off_cnt);
    int*  cursor = (int*)((char*)d_ws + off_cur);
    int2* sSD    = (int2*)((char*)d_ws + off_sd);
    int*  sE     = (int*)((char*)d_ws + off_se);

    setup_kernel<<<dim3(9), 256, 0, stream>>>(W, WhT, cnt);
    hist_kernel<<<dim3(HIST_BLOCKS), 256, 0, stream>>>(eidx, cnt, E);
    scan_kernel<<<dim3(1), 256, 0, stream>>>(cnt, cursor);

    int gemm_blocks = (N + GM - 1) / GM;
    dim3 gd(gemm_blocks + CONV_BLOCKS + SCAT_BLOCKS);
    fused_kernel<<<gd, 256, 0, stream>>>(x_out, x_in, WhT, Yh, Xh, eidx,
                                         sSD, sE, cursor, N, E, gemm_blocks);

    long long groups = ((long long)E + 1) / 2;
    unsigned eblocks = (unsigned)((groups * 16 + 255) / 256);
    edge_sorted_kernel<<<dim3(eblocks), 256, 0, stream>>>(Yh, Xh, sSD, sE, out, E);
  } else if (ws_size >= 2 * half_rows + wht_bytes) {
    __half* Yh  = (__half*)d_ws;
    __half* Xh  = (__half*)((char*)d_ws + half_rows);
    __half* WhT = (__half*)((char*)d_ws + 2 * half_rows);

    setup_kernel<<<dim3(8), 256, 0, stream>>>(W, WhT, (int*)WhT /*unused*/);

    int gemm_blocks = (N + GM - 1) / GM;
    dim3 g1(gemm_blocks + CONV_BLOCKS);
    prep2_kernel<<<g1, 256, 0, stream>>>(x_out, x_in, WhT, Yh, Xh, N, gemm_blocks);

    long long slots = ((long long)E + 1) / 2;
    long long total = slots * 16;
    dim3 g2((unsigned)((total + 255) / 256));
    edge_dot2_kernel<<<g2, 256, 0, stream>>>(Yh, Xh, eidx, out, E);
  } else {
    long long total = (long long)E * 64;
    dim3 g((unsigned)((total + 255) / 256));
    edge_bilinear_direct_kernel<<<g, 256, 0, stream>>>(x_out, x_in, W, eidx, out, E);
  }
}

// Round 3
// 247.161 us; speedup vs baseline: 2.8510x; 2.8510x over previous
//
#include <hip/hip_runtime.h>
#include <hip/hip_fp16.h>
#include <math.h>

#define D 128
#define GM 64            // rows per GEMM tile
#define CONV_BLOCKS 2048

typedef _Float16 f16x8 __attribute__((ext_vector_type(8)));
typedef float    f32x4 __attribute__((ext_vector_type(4)));
typedef _Float16 h2_t  __attribute__((ext_vector_type(2)));

__device__ __forceinline__ float dot2acc(unsigned ua, unsigned ub, float c) {
#if __has_builtin(__builtin_amdgcn_fdot2)
  return __builtin_amdgcn_fdot2(__builtin_bit_cast(h2_t, ua),
                                __builtin_bit_cast(h2_t, ub), c, false);
#else
  __half2 a = __builtin_bit_cast(__half2, ua);
  __half2 b = __builtin_bit_cast(__half2, ub);
  float2 fa = __half22float2(a), fb = __half22float2(b);
  return fmaf(fa.x, fb.x, fmaf(fa.y, fb.y, c));
#endif
}

__device__ __forceinline__ unsigned pack2(float x, float y) {
  __half2 h;
  h.x = __float2half_rn(x);
  h.y = __float2half_rn(y);
  return __builtin_bit_cast(unsigned, h);
}

// ---------------- Fused prep kernel (2-launch structure, 48 KB LDS) ----------
// blocks [0, gemm_blocks): one 64-row MFMA tile of Y = Xout @ W (fp16 out).
//   - A staged fp32->fp16 into XOR-swizzled LDS (q ^ (r&7): 2-way max, verified r1).
//   - W transposed per block into sB (fp32 k-major -> fp16 n-major, verified r0).
//   - Epilogue: acc -> sC (reuse sA) -> coalesced uint4 stores.
// blocks [gemm_blocks, +CONV_BLOCKS): grid-stride x_in fp32->fp16 convert.
__global__ __launch_bounds__(256) void prep3_kernel(
    const float* __restrict__ Xout, const float* __restrict__ Xin,
    const float* __restrict__ W, __half* __restrict__ Yh,
    __half* __restrict__ Xh, int N, int gemm_blocks)
{
  __shared__ __align__(16) __half sA[GM * D];     // 16 KB; reused as sC
  __shared__ __align__(16) __half sB[D * D];      // 32 KB

  const int tid = threadIdx.x;
  const int bid = blockIdx.x;

  if (bid >= gemm_blocks) {
    // ---- convert role: Xh = (half)Xin ----
    const int cb = bid - gemm_blocks;
    const int n4 = N * (D / 4);
    const int stride = CONV_BLOCKS * 256 * 4;
    for (int base = (cb * 256 + tid) * 4; base < n4; base += stride) {
      float4 v[4];
      #pragma unroll
      for (int j = 0; j < 4; j++)
        if (base + j < n4) v[j] = ((const float4*)Xin)[base + j];
      #pragma unroll
      for (int j = 0; j < 4; j++)
        if (base + j < n4) {
          uint2 u;
          u.x = pack2(v[j].x, v[j].y);
          u.y = pack2(v[j].z, v[j].w);
          ((uint2*)Xh)[base + j] = u;
        }
    }
    return;
  }

  // ---- GEMM role ----
  const int row0 = bid * GM;

  // Stage A: 1024 granules (16B fp16 = 32B fp32 src), 4 per thread.
  float4 v[8];
  #pragma unroll
  for (int i = 0; i < 4; i++) {
    int gi = tid + i * 256;            // granule id 0..1023
    int r = gi >> 4, q = gi & 15;
    int gr = row0 + r;
    if (gr < N) {
      const float4* s = (const float4*)(Xout + (size_t)gr * D + q * 8);
      v[2*i]   = s[0];
      v[2*i+1] = s[1];
    } else {
      v[2*i]   = make_float4(0.f, 0.f, 0.f, 0.f);
      v[2*i+1] = make_float4(0.f, 0.f, 0.f, 0.f);
    }
  }
  #pragma unroll
  for (int i = 0; i < 4; i++) {
    int gi = tid + i * 256;
    int r = gi >> 4, q = gi & 15;
    uint4 u;
    u.x = pack2(v[2*i].x,   v[2*i].y);
    u.y = pack2(v[2*i].z,   v[2*i].w);
    u.z = pack2(v[2*i+1].x, v[2*i+1].y);
    u.w = pack2(v[2*i+1].z, v[2*i+1].w);
    *(uint4*)(sA + r * D + ((q ^ (r & 7)) << 3)) = u;   // XOR swizzle (r1-verified)
  }

  // Stage B: transpose W (fp32 k-major) -> fp16 n-major swizzled LDS (r0-verified).
  #pragma unroll
  for (int i = 0; i < 64; i++) {
    int o = tid + i * 256;             // 0..16383
    int k = o >> 7;
    int n = o & 127;
    __half h = __float2half_rn(W[o]);
    int gk = k >> 3;
    sB[n * 128 + (((gk + n) & 15) << 3) + (k & 7)] = h;
  }
  __syncthreads();

  const int lane = tid & 63, wave = tid >> 6;
  const int m = lane & 15, quad = lane >> 4;
  const int rloc = wave * 16 + m;

  f32x4 acc[8];
  #pragma unroll
  for (int ct = 0; ct < 8; ct++) acc[ct] = (f32x4){0.f, 0.f, 0.f, 0.f};

  #pragma unroll
  for (int ks = 0; ks < 4; ks++) {
    const int g = ks * 4 + quad;       // k-granule: k = g*8 + j
    f16x8 bfrag[8];
    #pragma unroll
    for (int ct = 0; ct < 8; ct++) {
      int n = ct * 16 + m;
      bfrag[ct] = *(const f16x8*)(sB + n * 128 + (((g + n) & 15) << 3));
    }
    f16x8 afrag = *(const f16x8*)(sA + rloc * D + ((g ^ (rloc & 7)) << 3));
    #pragma unroll
    for (int ct = 0; ct < 8; ct++)
      acc[ct] = __builtin_amdgcn_mfma_f32_16x16x32_f16(
          afrag, bfrag[ct], acc[ct], 0, 0, 0);
  }

  // Epilogue: acc -> sC (reuse sA) -> coalesced uint4 stores.
  __syncthreads();
  __half* sC = sA;
  #pragma unroll
  for (int ct = 0; ct < 8; ct++)
    #pragma unroll
    for (int reg = 0; reg < 4; reg++) {
      int r = wave * 16 + quad * 4 + reg;
      sC[r * D + ct * 16 + m] = __float2half_rn(acc[ct][reg]);
    }
  __syncthreads();
  #pragma unroll
  for (int i = 0; i < 4; i++) {
    int gi = tid + i * 256;            // 0..1023 granules
    int r = gi >> 4, q = gi & 15;
    int gr = row0 + r;
    if (gr < N)
      *(uint4*)(Yh + (size_t)gr * D + q * 8) = *(const uint4*)(sC + r * D + q * 8);
  }
}

// ---------------- Edge kernel: out[e] = sigmoid(Yh[src] . Xh[dst]), 2 edges/thread
// (round-0 best-measured variant, verbatim)
__global__ __launch_bounds__(256) void edge_dot2_kernel(
    const __half* __restrict__ Yh, const __half* __restrict__ Xh,
    const int* __restrict__ idx, float* __restrict__ out, int E)
{
  long long gid = (long long)blockIdx.x * 256 + threadIdx.x;
  int slot = (int)(gid >> 4);
  int l    = (int)(gid & 15);
  int e0 = slot * 2;
  if (e0 >= E) return;
  int e1 = e0 + 1;
  bool has1 = (e1 < E);

  int s0 = idx[e0];
  int d0 = idx[E + e0];
  int s1 = has1 ? idx[e1] : s0;
  int d1 = has1 ? idx[E + e1] : d0;

  uint4 a0 = ((const uint4*)(Yh + (size_t)s0 * D))[l];
  uint4 b0 = ((const uint4*)(Xh + (size_t)d0 * D))[l];
  uint4 a1 = ((const uint4*)(Yh + (size_t)s1 * D))[l];
  uint4 b1 = ((const uint4*)(Xh + (size_t)d1 * D))[l];

  float p = 0.f, q = 0.f;
  p = dot2acc(a0.x, b0.x, p);  q = dot2acc(a1.x, b1.x, q);
  p = dot2acc(a0.y, b0.y, p);  q = dot2acc(a1.y, b1.y, q);
  p = dot2acc(a0.z, b0.z, p);  q = dot2acc(a1.z, b1.z, q);
  p = dot2acc(a0.w, b0.w, p);  q = dot2acc(a1.w, b1.w, q);

  p += __shfl_xor(p, 8);  q += __shfl_xor(q, 8);
  p += __shfl_xor(p, 4);  q += __shfl_xor(q, 4);
  p += __shfl_xor(p, 2);  q += __shfl_xor(q, 2);
  p += __shfl_xor(p, 1);  q += __shfl_xor(q, 1);

  if (l == 0) {
    float2 o;
    o.x = 1.0f / (1.0f + __expf(-p));
    o.y = 1.0f / (1.0f + __expf(-q));
    if (has1) *(float2*)(out + e0) = o;
    else      out[e0] = o.x;
  }
}

// ---------------- Fallback: direct bilinear per edge (only if ws too small) ----
__global__ __launch_bounds__(256) void edge_bilinear_direct_kernel(
    const float* __restrict__ Xout, const float* __restrict__ Xin,
    const float* __restrict__ W, const int* __restrict__ idx,
    float* __restrict__ out, int E)
{
  long long gid = (long long)blockIdx.x * 256 + threadIdx.x;
  int e = (int)(gid >> 6);
  if (e >= E) return;
  int l = (int)(gid & 63);

  int src = idx[e];
  int dst = idx[E + e];
  const float* a = Xout + (size_t)src * D;
  const float* b = Xin  + (size_t)dst * D;

  float s = 0.f;
  #pragma unroll
  for (int kk = 0; kk < 2; kk++) {
    int k = l + kk * 64;
    float ak = a[k];
    float t = 0.f;
    #pragma unroll 8
    for (int j = 0; j < D; j++) t = fmaf(W[(size_t)k * D + j], b[j], t);
    s = fmaf(ak, t, s);
  }
  #pragma unroll
  for (int off = 32; off >= 1; off >>= 1) s += __shfl_xor(s, off);
  if (l == 0) out[e] = 1.0f / (1.0f + __expf(-s));
}

extern "C" void kernel_launch(void* const* d_in, const int* in_sizes, int n_in,
                              void* d_out, int out_size, void* d_ws, size_t ws_size,
                              hipStream_t stream) {
  const float* x_in  = (const float*)d_in[0];   // [N, 128]
  const float* x_out = (const float*)d_in[1];   // [N, 128]
  const int*   eidx  = (const int*)d_in[2];     // [2, E]
  const float* W     = (const float*)d_in[3];   // [128,128]
  float* out = (float*)d_out;

  const int N = in_sizes[0] / D;
  const int E = in_sizes[2] / 2;

  const size_t half_rows = (size_t)N * D * sizeof(__half);  // 25.6 MB each

  if (ws_size >= 2 * half_rows) {
    __half* Yh = (__half*)d_ws;
    __half* Xh = (__half*)((char*)d_ws + half_rows);

    int gemm_blocks = (N + GM - 1) / GM;
    dim3 g1(gemm_blocks + CONV_BLOCKS);
    prep3_kernel<<<g1, 256, 0, stream>>>(x_out, x_in, W, Yh, Xh, N, gemm_blocks);

    long long slots = ((long long)E + 1) / 2;
    long long total = slots * 16;
    dim3 g2((unsigned)((total + 255) / 256));
    edge_dot2_kernel<<<g2, 256, 0, stream>>>(Yh, Xh, eidx, out, E);
  } else {
    long long total = (long long)E * 64;
    dim3 g((unsigned)((total + 255) / 256));
    edge_bilinear_direct_kernel<<<g, 256, 0, stream>>>(x_out, x_in, W, eidx, out, E);
  }
}